// Round 5
// baseline (17327.307 us; speedup 1.0000x reference)
//
#include <hip/hip_runtime.h>

// ============================================================================
// GCN link-prediction pipeline, fp32.
//   deg/dinv -> CSR(dst) build -> 4x (GEMM 128x128 + pull-aggregate)
//   -> U/V = h @ Wl1 halves -> per-pair logits + log_softmax
// R1 design (re-submitted; R2/R3/R4 benches all timed out at GPU acquisition):
//   k_gemm k-tiled (24.7KB LDS, 6 blk/CU vs R0's 98KB/1 blk);
//   k_aggregate: half-wave float4 rows (2 nodes/wave) + unroll-4 gather MLP;
//   k_pair: half-wave float4 rows (2 pairs/wave).
// ============================================================================

// ---------------- CSR build ----------------
__global__ void k_count(const int* __restrict__ dst, int* __restrict__ cnt, int E) {
  int i = blockIdx.x * blockDim.x + threadIdx.x;
  if (i < E) atomicAdd(&cnt[dst[i]], 1);
}

__global__ void k_dinv(const int* __restrict__ cnt, float* __restrict__ dinv, int n) {
  int i = blockIdx.x * blockDim.x + threadIdx.x;
  if (i < n) dinv[i] = rsqrtf((float)(cnt[i] + 1));  // +1 self-loop; deg>=1 always
}

#define SCHUNK 1024
__global__ void k_chunk_sum(const int* __restrict__ cnt, int* __restrict__ csum, int n) {
  __shared__ int sd[256];
  int c = blockIdx.x, t = threadIdx.x;
  int base = c * SCHUNK;
  int s = 0;
#pragma unroll
  for (int j = 0; j < 4; ++j) {
    int i = base + j * 256 + t;
    if (i < n) s += cnt[i];
  }
  sd[t] = s;
  __syncthreads();
  for (int off = 128; off > 0; off >>= 1) {
    if (t < off) sd[t] += sd[t + off];
    __syncthreads();
  }
  if (t == 0) csum[c] = sd[0];
}

__global__ void k_scan_partials(int* __restrict__ csum, int nc, int* __restrict__ offs, int n) {
  if (threadIdx.x == 0 && blockIdx.x == 0) {
    int run = 0;
    for (int i = 0; i < nc; ++i) { int v = csum[i]; csum[i] = run; run += v; }
    offs[n] = run;  // total = E
  }
}

__global__ void k_chunk_scan(const int* __restrict__ cnt, const int* __restrict__ csum,
                             int* __restrict__ offs, int n) {
  __shared__ int ts[256];
  int c = blockIdx.x, t = threadIdx.x;
  int i0 = c * SCHUNK + t * 4;
  int v0 = 0, v1 = 0, v2 = 0, v3 = 0;
  if (i0 + 0 < n) v0 = cnt[i0 + 0];
  if (i0 + 1 < n) v1 = cnt[i0 + 1];
  if (i0 + 2 < n) v2 = cnt[i0 + 2];
  if (i0 + 3 < n) v3 = cnt[i0 + 3];
  int s = v0 + v1 + v2 + v3;
  ts[t] = s;
  __syncthreads();
  for (int off = 1; off < 256; off <<= 1) {
    int x = (t >= off) ? ts[t - off] : 0;
    __syncthreads();
    ts[t] += x;
    __syncthreads();
  }
  int run = csum[c] + ts[t] - s;  // exclusive prefix for this thread
  if (i0 + 0 < n) { offs[i0 + 0] = run; run += v0; }
  if (i0 + 1 < n) { offs[i0 + 1] = run; run += v1; }
  if (i0 + 2 < n) { offs[i0 + 2] = run; run += v2; }
  if (i0 + 3 < n) { offs[i0 + 3] = run; run += v3; }
}

__global__ void k_fill(const int* __restrict__ src, const int* __restrict__ dst,
                       int* __restrict__ cursor, int* __restrict__ csr_src,
                       float* __restrict__ csr_w, const float* __restrict__ dinv, int E) {
  int i = blockIdx.x * blockDim.x + threadIdx.x;
  if (i >= E) return;
  int s = src[i], d = dst[i];
  int pos = atomicAdd(&cursor[d], 1);
  csr_src[pos] = s;
  csr_w[pos] = dinv[s] * dinv[d];
}

// ---------------- GEMM: O[M][ldo] = A[M][128] @ W[128][128] ----------------
// 64-row block tile, k-tiled by 32. LDS = 16KB (Ws) + 8.7KB (Xs) = 24.7KB
// -> 6 blocks/CU (24 waves) vs R0's 98KB/1 block. Thread tile 8x4.
__global__ __launch_bounds__(256) void k_gemm(const float* __restrict__ A,
                                              const float* __restrict__ W,
                                              float* __restrict__ O, int M, int ldo) {
  __shared__ float Ws[32 * 128];   // [kk][j]
  __shared__ float Xs[32 * 68];    // [kk][r] transposed, pad 68 (272B row, 16B-aligned)
  const int tid = threadIdx.x;
  const int row0 = blockIdx.x * 64;
  const int tx = tid & 31;  // cols tx*4 .. tx*4+3
  const int ty = tid >> 5;  // rows ty*8 .. ty*8+7
  float acc[8][4];
#pragma unroll
  for (int i = 0; i < 8; ++i)
#pragma unroll
    for (int j = 0; j < 4; ++j) acc[i][j] = 0.f;

#pragma unroll
  for (int kt = 0; kt < 4; ++kt) {
    // stage Ws: W rows kt*32..kt*32+31 (flat 4096 floats), coalesced float4
    const float* Wsrc = W + kt * 32 * 128;
#pragma unroll
    for (int i = 0; i < 4; ++i) {
      int idx = (tid + i * 256) * 4;
      *(float4*)(Ws + idx) = *(const float4*)(Wsrc + idx);
    }
    // stage Xs transposed: A rows row0..row0+63, cols kt*32..kt*32+31
#pragma unroll
    for (int it = 0; it < 2; ++it) {
      int r = it * 32 + (tid >> 3);
      int c4 = (tid & 7) * 4;
      int row = row0 + r;
      float4 v = make_float4(0.f, 0.f, 0.f, 0.f);
      if (row < M) v = *(const float4*)(A + (size_t)row * 128 + kt * 32 + c4);
      Xs[(c4 + 0) * 68 + r] = v.x;
      Xs[(c4 + 1) * 68 + r] = v.y;
      Xs[(c4 + 2) * 68 + r] = v.z;
      Xs[(c4 + 3) * 68 + r] = v.w;
    }
    __syncthreads();
#pragma unroll
    for (int kk = 0; kk < 32; ++kk) {
      float4 wv = *(const float4*)(Ws + kk * 128 + tx * 4);
      float4 xa = *(const float4*)(Xs + kk * 68 + ty * 8);
      float4 xb = *(const float4*)(Xs + kk * 68 + ty * 8 + 4);
      float xs[8] = {xa.x, xa.y, xa.z, xa.w, xb.x, xb.y, xb.z, xb.w};
      float wj[4] = {wv.x, wv.y, wv.z, wv.w};
#pragma unroll
      for (int i = 0; i < 8; ++i)
#pragma unroll
        for (int j = 0; j < 4; ++j) acc[i][j] = fmaf(xs[i], wj[j], acc[i][j]);
    }
    __syncthreads();
  }
#pragma unroll
  for (int i = 0; i < 8; ++i) {
    int row = row0 + ty * 8 + i;
    if (row < M) {
      float4 o;
      o.x = acc[i][0]; o.y = acc[i][1]; o.z = acc[i][2]; o.w = acc[i][3];
      *(float4*)(O + (size_t)row * ldo + tx * 4) = o;
    }
  }
}

// ---------------- Pull aggregation: H[i] = sum_e w_e*T[src_e] + dinv_i^2*T[i] + b
// 2 nodes per wave: half-wave (32 lanes x float4 = 512B row). Inner unroll x4
// -> 4 independent gathers in flight per half-wave.
__global__ __launch_bounds__(256) void k_aggregate(const float* __restrict__ T,
    float* __restrict__ H, const int* __restrict__ offs,
    const int* __restrict__ csr_src, const float* __restrict__ csr_w,
    const float* __restrict__ dinv, const float* __restrict__ bias,
    int n, int relu) {
  int gid = blockIdx.x * blockDim.x + threadIdx.x;
  int wave = gid >> 6;
  int lane = threadIdx.x & 63;
  int half = lane >> 5, l = lane & 31;
  int node = wave * 2 + half;
  bool act = node < n;
  int nd = act ? node : (n - 1);
  float di = dinv[nd];
  float w0 = di * di;
  float4 t0 = *(const float4*)(T + (size_t)nd * 128 + l * 4);
  float ax = t0.x * w0, ay = t0.y * w0, az = t0.z * w0, aw = t0.w * w0;
  int e0 = offs[nd], e1 = offs[nd + 1];
  int base = half << 5;
  for (int eb = e0; eb < e1; eb += 32) {
    int m = e1 - eb; if (m > 32) m = 32;
    int s = 0; float wv = 0.f;
    if (l < m) { s = csr_src[eb + l]; wv = csr_w[eb + l]; }
    int j = 0;
    for (; j + 4 <= m; j += 4) {
      int   s0 = __shfl(s,  base + j + 0); float q0 = __shfl(wv, base + j + 0);
      int   s1 = __shfl(s,  base + j + 1); float q1 = __shfl(wv, base + j + 1);
      int   s2 = __shfl(s,  base + j + 2); float q2 = __shfl(wv, base + j + 2);
      int   s3 = __shfl(s,  base + j + 3); float q3 = __shfl(wv, base + j + 3);
      float4 v0 = *(const float4*)(T + (size_t)s0 * 128 + l * 4);
      float4 v1 = *(const float4*)(T + (size_t)s1 * 128 + l * 4);
      float4 v2 = *(const float4*)(T + (size_t)s2 * 128 + l * 4);
      float4 v3 = *(const float4*)(T + (size_t)s3 * 128 + l * 4);
      ax = fmaf(v0.x, q0, fmaf(v1.x, q1, fmaf(v2.x, q2, fmaf(v3.x, q3, ax))));
      ay = fmaf(v0.y, q0, fmaf(v1.y, q1, fmaf(v2.y, q2, fmaf(v3.y, q3, ay))));
      az = fmaf(v0.z, q0, fmaf(v1.z, q1, fmaf(v2.z, q2, fmaf(v3.z, q3, az))));
      aw = fmaf(v0.w, q0, fmaf(v1.w, q1, fmaf(v2.w, q2, fmaf(v3.w, q3, aw))));
    }
    for (; j < m; ++j) {
      int   s0 = __shfl(s,  base + j); float q0 = __shfl(wv, base + j);
      float4 v0 = *(const float4*)(T + (size_t)s0 * 128 + l * 4);
      ax = fmaf(v0.x, q0, ax); ay = fmaf(v0.y, q0, ay);
      az = fmaf(v0.z, q0, az); aw = fmaf(v0.w, q0, aw);
    }
  }
  float4 bv = *(const float4*)(bias + l * 4);
  ax += bv.x; ay += bv.y; az += bv.z; aw += bv.w;
  if (relu) {
    ax = fmaxf(ax, 0.f); ay = fmaxf(ay, 0.f);
    az = fmaxf(az, 0.f); aw = fmaxf(aw, 0.f);
  }
  if (act) {
    float4 r; r.x = ax; r.y = ay; r.z = az; r.w = aw;
    *(float4*)(H + (size_t)node * 128 + l * 4) = r;
  }
}

// ---------------- Per-pair predictor: z=relu(U[a]+V[b]+bl1); logits=z@Wl2+bl2
// 2 pairs per wave: half-wave (32 lanes x float4 = 512B row).
__global__ __launch_bounds__(256) void k_pair(const float* __restrict__ UV,
    const int* __restrict__ pt, const int* __restrict__ nt,
    const int* __restrict__ ps, const int* __restrict__ ns,
    const float* __restrict__ bl1, const float* __restrict__ Wl2,
    const float* __restrict__ bl2, float* __restrict__ out,
    int npt, int nnt, int nps, int nns) {
  int gid = blockIdx.x * blockDim.x + threadIdx.x;
  int wave = gid >> 6;
  int lane = threadIdx.x & 63;
  int half = lane >> 5, l = lane & 31;
  int pidx = wave * 2 + half;
  int total = npt + nnt + nps + nns;
  bool act = pidx < total;
  int q = act ? pidx : 0;
  int a, b;
  if (q < npt)               { a = pt[q]; b = pt[npt + q]; }
  else if ((q -= npt) < nnt) { a = nt[q]; b = nt[nnt + q]; }
  else if ((q -= nnt) < nps) { a = ps[q]; b = ps[nps + q]; }
  else { q -= nps;             a = ns[q]; b = ns[nns + q]; }
  float4 u = *(const float4*)(UV + (size_t)a * 256 + l * 4);
  float4 v = *(const float4*)(UV + (size_t)b * 256 + 128 + l * 4);
  float4 bb = *(const float4*)(bl1 + l * 4);
  float z0 = fmaxf(u.x + v.x + bb.x, 0.f);
  float z1 = fmaxf(u.y + v.y + bb.y, 0.f);
  float z2 = fmaxf(u.z + v.z + bb.z, 0.f);
  float z3 = fmaxf(u.w + v.w + bb.w, 0.f);
  float4 wA = *(const float4*)(Wl2 + l * 8);      // rows 4l,4l+1 x {c0,c1}
  float4 wB = *(const float4*)(Wl2 + l * 8 + 4);  // rows 4l+2,4l+3
  float p0 = fmaf(z0, wA.x, fmaf(z1, wA.z, fmaf(z2, wB.x, z3 * wB.z)));
  float p1 = fmaf(z0, wA.y, fmaf(z1, wA.w, fmaf(z2, wB.y, z3 * wB.w)));
#pragma unroll
  for (int o = 16; o > 0; o >>= 1) {   // reduce within half-wave
    p0 += __shfl_xor(p0, o);
    p1 += __shfl_xor(p1, o);
  }
  if (l == 0 && act) {
    p0 += bl2[0]; p1 += bl2[1];
    float m = fmaxf(p0, p1);
    float lse = m + logf(expf(p0 - m) + expf(p1 - m));
    float2 r; r.x = p0 - lse; r.y = p1 - lse;
    *(float2*)(out + (size_t)pidx * 2) = r;
  }
}

// ============================================================================
extern "C" void kernel_launch(void* const* d_in, const int* in_sizes, int n_in,
                              void* d_out, int out_size, void* d_ws, size_t ws_size,
                              hipStream_t stream) {
  const float* x   = (const float*)d_in[0];
  const float* W0  = (const float*)d_in[1];
  const float* b0  = (const float*)d_in[2];
  const float* W1  = (const float*)d_in[3];
  const float* b1  = (const float*)d_in[4];
  const float* W2  = (const float*)d_in[5];
  const float* b2  = (const float*)d_in[6];
  const float* W3  = (const float*)d_in[7];
  const float* b3  = (const float*)d_in[8];
  const float* Wl1 = (const float*)d_in[9];
  const float* bl1 = (const float*)d_in[10];
  const float* Wl2 = (const float*)d_in[11];
  const float* bl2 = (const float*)d_in[12];
  const int* edge_index = (const int*)d_in[13];
  const int* pt = (const int*)d_in[14];
  const int* nt = (const int*)d_in[15];
  const int* ps = (const int*)d_in[16];
  const int* ns = (const int*)d_in[17];

  const int n   = in_sizes[0] / 128;
  const int E   = in_sizes[13] / 2;
  const int npt = in_sizes[14] / 2;
  const int nnt = in_sizes[15] / 2;
  const int nps = in_sizes[16] / 2;
  const int nns = in_sizes[17] / 2;
  float* out = (float*)d_out;

  // ---- workspace carve (all 256B-aligned regions) ----
  char* ws = (char*)d_ws;
  size_t off = 0;
  auto alloc = [&](size_t bytes) -> void* {
    void* p = ws + off;
    off += (bytes + 255) & ~(size_t)255;
    return p;
  };
  float* dinv    = (float*)alloc((size_t)n * 4);
  int*   cnt     = (int*)  alloc((size_t)n * 4);
  int*   offs    = (int*)  alloc((size_t)(n + 1) * 4);
  int*   cursor  = (int*)  alloc((size_t)n * 4);
  int*   csum    = (int*)  alloc(256 * 4);
  int*   csr_src = (int*)  alloc((size_t)E * 4);
  float* csr_w   = (float*)alloc((size_t)E * 4);
  float* bufA    = (float*)alloc((size_t)n * 128 * 4);
  float* bufB    = (float*)alloc((size_t)n * 128 * 4);
  float* UV      = (float*)alloc((size_t)n * 256 * 4);
  if (off > ws_size) return;  // insufficient scratch -> fail loudly (poisoned out)

  const int* esrc = edge_index;
  const int* edst = edge_index + E;

  // ---- degree + CSR ----
  hipMemsetAsync(cnt, 0, (size_t)n * 4, stream);
  k_count<<<(E + 255) / 256, 256, 0, stream>>>(edst, cnt, E);
  k_dinv<<<(n + 255) / 256, 256, 0, stream>>>(cnt, dinv, n);
  int nc = (n + SCHUNK - 1) / SCHUNK;
  k_chunk_sum<<<nc, 256, 0, stream>>>(cnt, csum, n);
  k_scan_partials<<<1, 64, 0, stream>>>(csum, nc, offs, n);
  k_chunk_scan<<<nc, 256, 0, stream>>>(cnt, csum, offs, n);
  hipMemcpyAsync(cursor, offs, (size_t)n * 4, hipMemcpyDeviceToDevice, stream);
  k_fill<<<(E + 255) / 256, 256, 0, stream>>>(esrc, edst, cursor, csr_src, csr_w, dinv, E);

  const int gblocks = (n + 63) / 64;
  const int awaves  = (n + 1) / 2;           // 2 nodes per wave
  const int ablocks = (awaves + 3) / 4;      // 4 waves/block

  // ---- 4 GCN layers ----
  k_gemm<<<gblocks, 256, 0, stream>>>(x, W0, bufB, n, 128);
  k_aggregate<<<ablocks, 256, 0, stream>>>(bufB, bufA, offs, csr_src, csr_w, dinv, b0, n, 1);
  k_gemm<<<gblocks, 256, 0, stream>>>(bufA, W1, bufB, n, 128);
  k_aggregate<<<ablocks, 256, 0, stream>>>(bufB, bufA, offs, csr_src, csr_w, dinv, b1, n, 1);
  k_gemm<<<gblocks, 256, 0, stream>>>(bufA, W2, bufB, n, 128);
  k_aggregate<<<ablocks, 256, 0, stream>>>(bufB, bufA, offs, csr_src, csr_w, dinv, b2, n, 1);
  k_gemm<<<gblocks, 256, 0, stream>>>(bufA, W3, bufB, n, 128);
  k_aggregate<<<ablocks, 256, 0, stream>>>(bufB, bufA, offs, csr_src, csr_w, dinv, b3, n, 0);

  // ---- U = h @ Wl1[:128], V = h @ Wl1[128:], interleaved as UV[n][256] ----
  k_gemm<<<gblocks, 256, 0, stream>>>(bufA, Wl1, UV, n, 256);
  k_gemm<<<gblocks, 256, 0, stream>>>(bufA, Wl1 + 128 * 128, UV + 128, n, 256);

  // ---- pairs -> log-softmax logits ----
  const int total = npt + nnt + nps + nns;
  const int pwaves = (total + 1) / 2;        // 2 pairs per wave
  k_pair<<<(pwaves + 3) / 4, 256, 0, stream>>>(UV, pt, nt, ps, ns, bl1, Wl2, bl2, out,
                                               npt, nnt, nps, nns);
}

// Round 6
// 1157.607 us; speedup vs baseline: 14.9682x; 14.9682x over previous
//
#include <hip/hip_runtime.h>

// ============================================================================
// GCN link-prediction pipeline, fp32.
//   deg/dinv -> CSR(dst) build -> 4x (GEMM 128x128 + pull-aggregate)
//   -> U/V = h @ Wl1 halves -> per-pair logits + log_softmax
// R5 fix: R1's k_gemm fully unrolled K=128 (unroll on kk nested in unrolled
// kt) -> 256 VGPR + scratch spill -> 4.6GB FETCH/dispatch, 2900us each.
// Restore bounded unroll: kt loop unroll 1, kk loop unroll 8 (R0's schedule)
// on the k-tiled 24.7KB-LDS structure. Everything else unchanged from R1.
// ============================================================================

// ---------------- CSR build ----------------
__global__ void k_count(const int* __restrict__ dst, int* __restrict__ cnt, int E) {
  int i = blockIdx.x * blockDim.x + threadIdx.x;
  if (i < E) atomicAdd(&cnt[dst[i]], 1);
}

__global__ void k_dinv(const int* __restrict__ cnt, float* __restrict__ dinv, int n) {
  int i = blockIdx.x * blockDim.x + threadIdx.x;
  if (i < n) dinv[i] = rsqrtf((float)(cnt[i] + 1));  // +1 self-loop; deg>=1 always
}

#define SCHUNK 1024
__global__ void k_chunk_sum(const int* __restrict__ cnt, int* __restrict__ csum, int n) {
  __shared__ int sd[256];
  int c = blockIdx.x, t = threadIdx.x;
  int base = c * SCHUNK;
  int s = 0;
#pragma unroll
  for (int j = 0; j < 4; ++j) {
    int i = base + j * 256 + t;
    if (i < n) s += cnt[i];
  }
  sd[t] = s;
  __syncthreads();
  for (int off = 128; off > 0; off >>= 1) {
    if (t < off) sd[t] += sd[t + off];
    __syncthreads();
  }
  if (t == 0) csum[c] = sd[0];
}

__global__ void k_scan_partials(int* __restrict__ csum, int nc, int* __restrict__ offs, int n) {
  if (threadIdx.x == 0 && blockIdx.x == 0) {
    int run = 0;
    for (int i = 0; i < nc; ++i) { int v = csum[i]; csum[i] = run; run += v; }
    offs[n] = run;  // total = E
  }
}

__global__ void k_chunk_scan(const int* __restrict__ cnt, const int* __restrict__ csum,
                             int* __restrict__ offs, int n) {
  __shared__ int ts[256];
  int c = blockIdx.x, t = threadIdx.x;
  int i0 = c * SCHUNK + t * 4;
  int v0 = 0, v1 = 0, v2 = 0, v3 = 0;
  if (i0 + 0 < n) v0 = cnt[i0 + 0];
  if (i0 + 1 < n) v1 = cnt[i0 + 1];
  if (i0 + 2 < n) v2 = cnt[i0 + 2];
  if (i0 + 3 < n) v3 = cnt[i0 + 3];
  int s = v0 + v1 + v2 + v3;
  ts[t] = s;
  __syncthreads();
  for (int off = 1; off < 256; off <<= 1) {
    int x = (t >= off) ? ts[t - off] : 0;
    __syncthreads();
    ts[t] += x;
    __syncthreads();
  }
  int run = csum[c] + ts[t] - s;  // exclusive prefix for this thread
  if (i0 + 0 < n) { offs[i0 + 0] = run; run += v0; }
  if (i0 + 1 < n) { offs[i0 + 1] = run; run += v1; }
  if (i0 + 2 < n) { offs[i0 + 2] = run; run += v2; }
  if (i0 + 3 < n) { offs[i0 + 3] = run; run += v3; }
}

__global__ void k_fill(const int* __restrict__ src, const int* __restrict__ dst,
                       int* __restrict__ cursor, int* __restrict__ csr_src,
                       float* __restrict__ csr_w, const float* __restrict__ dinv, int E) {
  int i = blockIdx.x * blockDim.x + threadIdx.x;
  if (i >= E) return;
  int s = src[i], d = dst[i];
  int pos = atomicAdd(&cursor[d], 1);
  csr_src[pos] = s;
  csr_w[pos] = dinv[s] * dinv[d];
}

// ---------------- GEMM: O[M][ldo] = A[M][128] @ W[128][128] ----------------
// 64-row block tile, k-tiled by 32. LDS = 16KB (Ws) + 8.7KB (Xs) = 24.7KB.
// Thread tile 8 rows x 4 cols. kt loop unroll 1 + kk loop unroll 8: bounded
// register pressure (R1's full unroll spilled to scratch: 256 VGPR, 4.6GB
// FETCH, 2900us/dispatch).
__global__ __launch_bounds__(256) void k_gemm(const float* __restrict__ A,
                                              const float* __restrict__ W,
                                              float* __restrict__ O, int M, int ldo) {
  __shared__ float Ws[32 * 128];   // [kk][j]
  __shared__ float Xs[32 * 68];    // [kk][r] transposed, pad 68 (272B row, 16B-aligned)
  const int tid = threadIdx.x;
  const int row0 = blockIdx.x * 64;
  const int tx = tid & 31;  // cols tx*4 .. tx*4+3
  const int ty = tid >> 5;  // rows ty*8 .. ty*8+7
  float acc[8][4];
#pragma unroll
  for (int i = 0; i < 8; ++i)
#pragma unroll
    for (int j = 0; j < 4; ++j) acc[i][j] = 0.f;

#pragma unroll 1
  for (int kt = 0; kt < 4; ++kt) {
    // stage Ws: W rows kt*32..kt*32+31 (flat 4096 floats), coalesced float4
    const float* Wsrc = W + kt * 32 * 128;
#pragma unroll
    for (int i = 0; i < 4; ++i) {
      int idx = (tid + i * 256) * 4;
      *(float4*)(Ws + idx) = *(const float4*)(Wsrc + idx);
    }
    // stage Xs transposed: A rows row0..row0+63, cols kt*32..kt*32+31
#pragma unroll
    for (int it = 0; it < 2; ++it) {
      int r = it * 32 + (tid >> 3);
      int c4 = (tid & 7) * 4;
      int row = row0 + r;
      float4 v = make_float4(0.f, 0.f, 0.f, 0.f);
      if (row < M) v = *(const float4*)(A + (size_t)row * 128 + kt * 32 + c4);
      Xs[(c4 + 0) * 68 + r] = v.x;
      Xs[(c4 + 1) * 68 + r] = v.y;
      Xs[(c4 + 2) * 68 + r] = v.z;
      Xs[(c4 + 3) * 68 + r] = v.w;
    }
    __syncthreads();
#pragma unroll 8
    for (int kk = 0; kk < 32; ++kk) {
      float4 wv = *(const float4*)(Ws + kk * 128 + tx * 4);
      float4 xa = *(const float4*)(Xs + kk * 68 + ty * 8);
      float4 xb = *(const float4*)(Xs + kk * 68 + ty * 8 + 4);
      float xs[8] = {xa.x, xa.y, xa.z, xa.w, xb.x, xb.y, xb.z, xb.w};
      float wj[4] = {wv.x, wv.y, wv.z, wv.w};
#pragma unroll
      for (int i = 0; i < 8; ++i)
#pragma unroll
        for (int j = 0; j < 4; ++j) acc[i][j] = fmaf(xs[i], wj[j], acc[i][j]);
    }
    __syncthreads();
  }
#pragma unroll
  for (int i = 0; i < 8; ++i) {
    int row = row0 + ty * 8 + i;
    if (row < M) {
      float4 o;
      o.x = acc[i][0]; o.y = acc[i][1]; o.z = acc[i][2]; o.w = acc[i][3];
      *(float4*)(O + (size_t)row * ldo + tx * 4) = o;
    }
  }
}

// ---------------- Pull aggregation: H[i] = sum_e w_e*T[src_e] + dinv_i^2*T[i] + b
// 2 nodes per wave: half-wave (32 lanes x float4 = 512B row). Inner unroll x4
// -> 4 independent gathers in flight per half-wave.
__global__ __launch_bounds__(256) void k_aggregate(const float* __restrict__ T,
    float* __restrict__ H, const int* __restrict__ offs,
    const int* __restrict__ csr_src, const float* __restrict__ csr_w,
    const float* __restrict__ dinv, const float* __restrict__ bias,
    int n, int relu) {
  int gid = blockIdx.x * blockDim.x + threadIdx.x;
  int wave = gid >> 6;
  int lane = threadIdx.x & 63;
  int half = lane >> 5, l = lane & 31;
  int node = wave * 2 + half;
  bool act = node < n;
  int nd = act ? node : (n - 1);
  float di = dinv[nd];
  float w0 = di * di;
  float4 t0 = *(const float4*)(T + (size_t)nd * 128 + l * 4);
  float ax = t0.x * w0, ay = t0.y * w0, az = t0.z * w0, aw = t0.w * w0;
  int e0 = offs[nd], e1 = offs[nd + 1];
  int base = half << 5;
  for (int eb = e0; eb < e1; eb += 32) {
    int m = e1 - eb; if (m > 32) m = 32;
    int s = 0; float wv = 0.f;
    if (l < m) { s = csr_src[eb + l]; wv = csr_w[eb + l]; }
    int j = 0;
    for (; j + 4 <= m; j += 4) {
      int   s0 = __shfl(s,  base + j + 0); float q0 = __shfl(wv, base + j + 0);
      int   s1 = __shfl(s,  base + j + 1); float q1 = __shfl(wv, base + j + 1);
      int   s2 = __shfl(s,  base + j + 2); float q2 = __shfl(wv, base + j + 2);
      int   s3 = __shfl(s,  base + j + 3); float q3 = __shfl(wv, base + j + 3);
      float4 v0 = *(const float4*)(T + (size_t)s0 * 128 + l * 4);
      float4 v1 = *(const float4*)(T + (size_t)s1 * 128 + l * 4);
      float4 v2 = *(const float4*)(T + (size_t)s2 * 128 + l * 4);
      float4 v3 = *(const float4*)(T + (size_t)s3 * 128 + l * 4);
      ax = fmaf(v0.x, q0, fmaf(v1.x, q1, fmaf(v2.x, q2, fmaf(v3.x, q3, ax))));
      ay = fmaf(v0.y, q0, fmaf(v1.y, q1, fmaf(v2.y, q2, fmaf(v3.y, q3, ay))));
      az = fmaf(v0.z, q0, fmaf(v1.z, q1, fmaf(v2.z, q2, fmaf(v3.z, q3, az))));
      aw = fmaf(v0.w, q0, fmaf(v1.w, q1, fmaf(v2.w, q2, fmaf(v3.w, q3, aw))));
    }
    for (; j < m; ++j) {
      int   s0 = __shfl(s,  base + j); float q0 = __shfl(wv, base + j);
      float4 v0 = *(const float4*)(T + (size_t)s0 * 128 + l * 4);
      ax = fmaf(v0.x, q0, ax); ay = fmaf(v0.y, q0, ay);
      az = fmaf(v0.z, q0, az); aw = fmaf(v0.w, q0, aw);
    }
  }
  float4 bv = *(const float4*)(bias + l * 4);
  ax += bv.x; ay += bv.y; az += bv.z; aw += bv.w;
  if (relu) {
    ax = fmaxf(ax, 0.f); ay = fmaxf(ay, 0.f);
    az = fmaxf(az, 0.f); aw = fmaxf(aw, 0.f);
  }
  if (act) {
    float4 r; r.x = ax; r.y = ay; r.z = az; r.w = aw;
    *(float4*)(H + (size_t)node * 128 + l * 4) = r;
  }
}

// ---------------- Per-pair predictor: z=relu(U[a]+V[b]+bl1); logits=z@Wl2+bl2
// 2 pairs per wave: half-wave (32 lanes x float4 = 512B row).
__global__ __launch_bounds__(256) void k_pair(const float* __restrict__ UV,
    const int* __restrict__ pt, const int* __restrict__ nt,
    const int* __restrict__ ps, const int* __restrict__ ns,
    const float* __restrict__ bl1, const float* __restrict__ Wl2,
    const float* __restrict__ bl2, float* __restrict__ out,
    int npt, int nnt, int nps, int nns) {
  int gid = blockIdx.x * blockDim.x + threadIdx.x;
  int wave = gid >> 6;
  int lane = threadIdx.x & 63;
  int half = lane >> 5, l = lane & 31;
  int pidx = wave * 2 + half;
  int total = npt + nnt + nps + nns;
  bool act = pidx < total;
  int q = act ? pidx : 0;
  int a, b;
  if (q < npt)               { a = pt[q]; b = pt[npt + q]; }
  else if ((q -= npt) < nnt) { a = nt[q]; b = nt[nnt + q]; }
  else if ((q -= nnt) < nps) { a = ps[q]; b = ps[nps + q]; }
  else { q -= nps;             a = ns[q]; b = ns[nns + q]; }
  float4 u = *(const float4*)(UV + (size_t)a * 256 + l * 4);
  float4 v = *(const float4*)(UV + (size_t)b * 256 + 128 + l * 4);
  float4 bb = *(const float4*)(bl1 + l * 4);
  float z0 = fmaxf(u.x + v.x + bb.x, 0.f);
  float z1 = fmaxf(u.y + v.y + bb.y, 0.f);
  float z2 = fmaxf(u.z + v.z + bb.z, 0.f);
  float z3 = fmaxf(u.w + v.w + bb.w, 0.f);
  float4 wA = *(const float4*)(Wl2 + l * 8);      // rows 4l,4l+1 x {c0,c1}
  float4 wB = *(const float4*)(Wl2 + l * 8 + 4);  // rows 4l+2,4l+3
  float p0 = fmaf(z0, wA.x, fmaf(z1, wA.z, fmaf(z2, wB.x, z3 * wB.z)));
  float p1 = fmaf(z0, wA.y, fmaf(z1, wA.w, fmaf(z2, wB.y, z3 * wB.w)));
#pragma unroll
  for (int o = 16; o > 0; o >>= 1) {   // reduce within half-wave
    p0 += __shfl_xor(p0, o);
    p1 += __shfl_xor(p1, o);
  }
  if (l == 0 && act) {
    p0 += bl2[0]; p1 += bl2[1];
    float m = fmaxf(p0, p1);
    float lse = m + logf(expf(p0 - m) + expf(p1 - m));
    float2 r; r.x = p0 - lse; r.y = p1 - lse;
    *(float2*)(out + (size_t)pidx * 2) = r;
  }
}

// ============================================================================
extern "C" void kernel_launch(void* const* d_in, const int* in_sizes, int n_in,
                              void* d_out, int out_size, void* d_ws, size_t ws_size,
                              hipStream_t stream) {
  const float* x   = (const float*)d_in[0];
  const float* W0  = (const float*)d_in[1];
  const float* b0  = (const float*)d_in[2];
  const float* W1  = (const float*)d_in[3];
  const float* b1  = (const float*)d_in[4];
  const float* W2  = (const float*)d_in[5];
  const float* b2  = (const float*)d_in[6];
  const float* W3  = (const float*)d_in[7];
  const float* b3  = (const float*)d_in[8];
  const float* Wl1 = (const float*)d_in[9];
  const float* bl1 = (const float*)d_in[10];
  const float* Wl2 = (const float*)d_in[11];
  const float* bl2 = (const float*)d_in[12];
  const int* edge_index = (const int*)d_in[13];
  const int* pt = (const int*)d_in[14];
  const int* nt = (const int*)d_in[15];
  const int* ps = (const int*)d_in[16];
  const int* ns = (const int*)d_in[17];

  const int n   = in_sizes[0] / 128;
  const int E   = in_sizes[13] / 2;
  const int npt = in_sizes[14] / 2;
  const int nnt = in_sizes[15] / 2;
  const int nps = in_sizes[16] / 2;
  const int nns = in_sizes[17] / 2;
  float* out = (float*)d_out;

  // ---- workspace carve (all 256B-aligned regions) ----
  char* ws = (char*)d_ws;
  size_t off = 0;
  auto alloc = [&](size_t bytes) -> void* {
    void* p = ws + off;
    off += (bytes + 255) & ~(size_t)255;
    return p;
  };
  float* dinv    = (float*)alloc((size_t)n * 4);
  int*   cnt     = (int*)  alloc((size_t)n * 4);
  int*   offs    = (int*)  alloc((size_t)(n + 1) * 4);
  int*   cursor  = (int*)  alloc((size_t)n * 4);
  int*   csum    = (int*)  alloc(256 * 4);
  int*   csr_src = (int*)  alloc((size_t)E * 4);
  float* csr_w   = (float*)alloc((size_t)E * 4);
  float* bufA    = (float*)alloc((size_t)n * 128 * 4);
  float* bufB    = (float*)alloc((size_t)n * 128 * 4);
  float* UV      = (float*)alloc((size_t)n * 256 * 4);
  if (off > ws_size) return;  // insufficient scratch -> fail loudly (poisoned out)

  const int* esrc = edge_index;
  const int* edst = edge_index + E;

  // ---- degree + CSR ----
  hipMemsetAsync(cnt, 0, (size_t)n * 4, stream);
  k_count<<<(E + 255) / 256, 256, 0, stream>>>(edst, cnt, E);
  k_dinv<<<(n + 255) / 256, 256, 0, stream>>>(cnt, dinv, n);
  int nc = (n + SCHUNK - 1) / SCHUNK;
  k_chunk_sum<<<nc, 256, 0, stream>>>(cnt, csum, n);
  k_scan_partials<<<1, 64, 0, stream>>>(csum, nc, offs, n);
  k_chunk_scan<<<nc, 256, 0, stream>>>(cnt, csum, offs, n);
  hipMemcpyAsync(cursor, offs, (size_t)n * 4, hipMemcpyDeviceToDevice, stream);
  k_fill<<<(E + 255) / 256, 256, 0, stream>>>(esrc, edst, cursor, csr_src, csr_w, dinv, E);

  const int gblocks = (n + 63) / 64;
  const int awaves  = (n + 1) / 2;           // 2 nodes per wave
  const int ablocks = (awaves + 3) / 4;      // 4 waves/block

  // ---- 4 GCN layers ----
  k_gemm<<<gblocks, 256, 0, stream>>>(x, W0, bufB, n, 128);
  k_aggregate<<<ablocks, 256, 0, stream>>>(bufB, bufA, offs, csr_src, csr_w, dinv, b0, n, 1);
  k_gemm<<<gblocks, 256, 0, stream>>>(bufA, W1, bufB, n, 128);
  k_aggregate<<<ablocks, 256, 0, stream>>>(bufB, bufA, offs, csr_src, csr_w, dinv, b1, n, 1);
  k_gemm<<<gblocks, 256, 0, stream>>>(bufA, W2, bufB, n, 128);
  k_aggregate<<<ablocks, 256, 0, stream>>>(bufB, bufA, offs, csr_src, csr_w, dinv, b2, n, 1);
  k_gemm<<<gblocks, 256, 0, stream>>>(bufA, W3, bufB, n, 128);
  k_aggregate<<<ablocks, 256, 0, stream>>>(bufB, bufA, offs, csr_src, csr_w, dinv, b3, n, 0);

  // ---- U = h @ Wl1[:128], V = h @ Wl1[128:], interleaved as UV[n][256] ----
  k_gemm<<<gblocks, 256, 0, stream>>>(bufA, Wl1, UV, n, 256);
  k_gemm<<<gblocks, 256, 0, stream>>>(bufA, Wl1 + 128 * 128, UV + 128, n, 256);

  // ---- pairs -> log-softmax logits ----
  const int total = npt + nnt + nps + nns;
  const int pwaves = (total + 1) / 2;        // 2 pairs per wave
  k_pair<<<(pwaves + 3) / 4, 256, 0, stream>>>(UV, pt, nt, ps, ns, bl1, Wl2, bl2, out,
                                               npt, nnt, nps, nns);
}

// Round 7
// 912.135 us; speedup vs baseline: 18.9964x; 1.2691x over previous
//
#include <hip/hip_runtime.h>
#include <hip/hip_fp16.h>

// ============================================================================
// GCN link-prediction pipeline.
//   deg/dinv -> CSR(dst) build -> 4x (GEMM 128x128 fp32->fp16 + pull-aggregate
//   fp16-gather/fp32-accum) -> U/V fp16 -> per-pair logits + log_softmax fp32.
// R6 history: R5 spill fix -> 1157us; profile showed 4x k_aggregate @125us
// (FETCH 403MB @3.7TB/s, VALU 11%) = random-gather BW-bound.
// R6 change: intermediate T rows + UV in fp16 (256B/edge instead of 512B).
// Accumulation stays fp32; one fp16 rounding per layer. Expected absmax ~1e-3.
// ============================================================================

// ---------------- CSR build ----------------
__global__ void k_count(const int* __restrict__ dst, int* __restrict__ cnt, int E) {
  int i = blockIdx.x * blockDim.x + threadIdx.x;
  if (i < E) atomicAdd(&cnt[dst[i]], 1);
}

__global__ void k_dinv(const int* __restrict__ cnt, float* __restrict__ dinv, int n) {
  int i = blockIdx.x * blockDim.x + threadIdx.x;
  if (i < n) dinv[i] = rsqrtf((float)(cnt[i] + 1));  // +1 self-loop; deg>=1 always
}

#define SCHUNK 1024
__global__ void k_chunk_sum(const int* __restrict__ cnt, int* __restrict__ csum, int n) {
  __shared__ int sd[256];
  int c = blockIdx.x, t = threadIdx.x;
  int base = c * SCHUNK;
  int s = 0;
#pragma unroll
  for (int j = 0; j < 4; ++j) {
    int i = base + j * 256 + t;
    if (i < n) s += cnt[i];
  }
  sd[t] = s;
  __syncthreads();
  for (int off = 128; off > 0; off >>= 1) {
    if (t < off) sd[t] += sd[t + off];
    __syncthreads();
  }
  if (t == 0) csum[c] = sd[0];
}

__global__ void k_scan_partials(int* __restrict__ csum, int nc, int* __restrict__ offs, int n) {
  if (threadIdx.x == 0 && blockIdx.x == 0) {
    int run = 0;
    for (int i = 0; i < nc; ++i) { int v = csum[i]; csum[i] = run; run += v; }
    offs[n] = run;  // total = E
  }
}

__global__ void k_chunk_scan(const int* __restrict__ cnt, const int* __restrict__ csum,
                             int* __restrict__ offs, int n) {
  __shared__ int ts[256];
  int c = blockIdx.x, t = threadIdx.x;
  int i0 = c * SCHUNK + t * 4;
  int v0 = 0, v1 = 0, v2 = 0, v3 = 0;
  if (i0 + 0 < n) v0 = cnt[i0 + 0];
  if (i0 + 1 < n) v1 = cnt[i0 + 1];
  if (i0 + 2 < n) v2 = cnt[i0 + 2];
  if (i0 + 3 < n) v3 = cnt[i0 + 3];
  int s = v0 + v1 + v2 + v3;
  ts[t] = s;
  __syncthreads();
  for (int off = 1; off < 256; off <<= 1) {
    int x = (t >= off) ? ts[t - off] : 0;
    __syncthreads();
    ts[t] += x;
    __syncthreads();
  }
  int run = csum[c] + ts[t] - s;  // exclusive prefix for this thread
  if (i0 + 0 < n) { offs[i0 + 0] = run; run += v0; }
  if (i0 + 1 < n) { offs[i0 + 1] = run; run += v1; }
  if (i0 + 2 < n) { offs[i0 + 2] = run; run += v2; }
  if (i0 + 3 < n) { offs[i0 + 3] = run; run += v3; }
}

__global__ void k_fill(const int* __restrict__ src, const int* __restrict__ dst,
                       int* __restrict__ cursor, int* __restrict__ csr_src,
                       float* __restrict__ csr_w, const float* __restrict__ dinv, int E) {
  int i = blockIdx.x * blockDim.x + threadIdx.x;
  if (i >= E) return;
  int s = src[i], d = dst[i];
  int pos = atomicAdd(&cursor[d], 1);
  csr_src[pos] = s;
  csr_w[pos] = dinv[s] * dinv[d];
}

// ---------------- GEMM: O[M][ldo](fp16) = A[M][128](fp32) @ W[128][128](fp32)
// 64-row block tile, k-tiled by 32. LDS 24.7KB. kt unroll 1 + kk unroll 8
// (bounded VGPR; R1's full unroll spilled). Output rounded to fp16 (R6).
__global__ __launch_bounds__(256) void k_gemm(const float* __restrict__ A,
                                              const float* __restrict__ W,
                                              __half* __restrict__ O, int M, int ldo) {
  __shared__ float Ws[32 * 128];   // [kk][j]
  __shared__ float Xs[32 * 68];    // [kk][r] transposed, pad 68
  const int tid = threadIdx.x;
  const int row0 = blockIdx.x * 64;
  const int tx = tid & 31;  // cols tx*4 .. tx*4+3
  const int ty = tid >> 5;  // rows ty*8 .. ty*8+7
  float acc[8][4];
#pragma unroll
  for (int i = 0; i < 8; ++i)
#pragma unroll
    for (int j = 0; j < 4; ++j) acc[i][j] = 0.f;

#pragma unroll 1
  for (int kt = 0; kt < 4; ++kt) {
    const float* Wsrc = W + kt * 32 * 128;
#pragma unroll
    for (int i = 0; i < 4; ++i) {
      int idx = (tid + i * 256) * 4;
      *(float4*)(Ws + idx) = *(const float4*)(Wsrc + idx);
    }
#pragma unroll
    for (int it = 0; it < 2; ++it) {
      int r = it * 32 + (tid >> 3);
      int c4 = (tid & 7) * 4;
      int row = row0 + r;
      float4 v = make_float4(0.f, 0.f, 0.f, 0.f);
      if (row < M) v = *(const float4*)(A + (size_t)row * 128 + kt * 32 + c4);
      Xs[(c4 + 0) * 68 + r] = v.x;
      Xs[(c4 + 1) * 68 + r] = v.y;
      Xs[(c4 + 2) * 68 + r] = v.z;
      Xs[(c4 + 3) * 68 + r] = v.w;
    }
    __syncthreads();
#pragma unroll 8
    for (int kk = 0; kk < 32; ++kk) {
      float4 wv = *(const float4*)(Ws + kk * 128 + tx * 4);
      float4 xa = *(const float4*)(Xs + kk * 68 + ty * 8);
      float4 xb = *(const float4*)(Xs + kk * 68 + ty * 8 + 4);
      float xs[8] = {xa.x, xa.y, xa.z, xa.w, xb.x, xb.y, xb.z, xb.w};
      float wj[4] = {wv.x, wv.y, wv.z, wv.w};
#pragma unroll
      for (int i = 0; i < 8; ++i)
#pragma unroll
        for (int j = 0; j < 4; ++j) acc[i][j] = fmaf(xs[i], wj[j], acc[i][j]);
    }
    __syncthreads();
  }
#pragma unroll
  for (int i = 0; i < 8; ++i) {
    int row = row0 + ty * 8 + i;
    if (row < M) {
      __half2 a01 = __floats2half2_rn(acc[i][0], acc[i][1]);
      __half2 a23 = __floats2half2_rn(acc[i][2], acc[i][3]);
      uint2 pk;
      pk.x = *reinterpret_cast<unsigned int*>(&a01);
      pk.y = *reinterpret_cast<unsigned int*>(&a23);
      *reinterpret_cast<uint2*>(O + (size_t)row * ldo + tx * 4) = pk;
    }
  }
}

// ---------------- Pull aggregation: H[i] = sum_e w_e*T[src_e] + dinv_i^2*T[i] + b
// T in fp16 (256B/row gather), fp32 accumulate, H out fp32.
// 2 nodes per wave: half-wave = 32 lanes x uint2(4 halves). Unroll x4.
__global__ __launch_bounds__(256) void k_aggregate(const __half* __restrict__ T,
    float* __restrict__ H, const int* __restrict__ offs,
    const int* __restrict__ csr_src, const float* __restrict__ csr_w,
    const float* __restrict__ dinv, const float* __restrict__ bias,
    int n, int relu) {
  int gid = blockIdx.x * blockDim.x + threadIdx.x;
  int wave = gid >> 6;
  int lane = threadIdx.x & 63;
  int half = lane >> 5, l = lane & 31;
  int node = wave * 2 + half;
  bool act = node < n;
  int nd = act ? node : (n - 1);
  float di = dinv[nd];
  float w0 = di * di;
  uint2 tr = *(const uint2*)(T + (size_t)nd * 128 + l * 4);
  float2 t01 = __half22float2(*reinterpret_cast<const __half2*>(&tr.x));
  float2 t23 = __half22float2(*reinterpret_cast<const __half2*>(&tr.y));
  float ax = t01.x * w0, ay = t01.y * w0, az = t23.x * w0, aw = t23.y * w0;
  int e0 = offs[nd], e1 = offs[nd + 1];
  int base = half << 5;
  for (int eb = e0; eb < e1; eb += 32) {
    int m = e1 - eb; if (m > 32) m = 32;
    int s = 0; float wv = 0.f;
    if (l < m) { s = csr_src[eb + l]; wv = csr_w[eb + l]; }
    int j = 0;
    for (; j + 4 <= m; j += 4) {
      int   s0 = __shfl(s,  base + j + 0); float q0 = __shfl(wv, base + j + 0);
      int   s1 = __shfl(s,  base + j + 1); float q1 = __shfl(wv, base + j + 1);
      int   s2 = __shfl(s,  base + j + 2); float q2 = __shfl(wv, base + j + 2);
      int   s3 = __shfl(s,  base + j + 3); float q3 = __shfl(wv, base + j + 3);
      uint2 r0 = *(const uint2*)(T + (size_t)s0 * 128 + l * 4);
      uint2 r1 = *(const uint2*)(T + (size_t)s1 * 128 + l * 4);
      uint2 r2 = *(const uint2*)(T + (size_t)s2 * 128 + l * 4);
      uint2 r3 = *(const uint2*)(T + (size_t)s3 * 128 + l * 4);
      float2 a0 = __half22float2(*reinterpret_cast<const __half2*>(&r0.x));
      float2 b0 = __half22float2(*reinterpret_cast<const __half2*>(&r0.y));
      float2 a1 = __half22float2(*reinterpret_cast<const __half2*>(&r1.x));
      float2 b1 = __half22float2(*reinterpret_cast<const __half2*>(&r1.y));
      float2 a2 = __half22float2(*reinterpret_cast<const __half2*>(&r2.x));
      float2 b2 = __half22float2(*reinterpret_cast<const __half2*>(&r2.y));
      float2 a3 = __half22float2(*reinterpret_cast<const __half2*>(&r3.x));
      float2 b3 = __half22float2(*reinterpret_cast<const __half2*>(&r3.y));
      ax = fmaf(a0.x, q0, fmaf(a1.x, q1, fmaf(a2.x, q2, fmaf(a3.x, q3, ax))));
      ay = fmaf(a0.y, q0, fmaf(a1.y, q1, fmaf(a2.y, q2, fmaf(a3.y, q3, ay))));
      az = fmaf(b0.x, q0, fmaf(b1.x, q1, fmaf(b2.x, q2, fmaf(b3.x, q3, az))));
      aw = fmaf(b0.y, q0, fmaf(b1.y, q1, fmaf(b2.y, q2, fmaf(b3.y, q3, aw))));
    }
    for (; j < m; ++j) {
      int   s0 = __shfl(s,  base + j); float q0 = __shfl(wv, base + j);
      uint2 r0 = *(const uint2*)(T + (size_t)s0 * 128 + l * 4);
      float2 a0 = __half22float2(*reinterpret_cast<const __half2*>(&r0.x));
      float2 b0 = __half22float2(*reinterpret_cast<const __half2*>(&r0.y));
      ax = fmaf(a0.x, q0, ax); ay = fmaf(a0.y, q0, ay);
      az = fmaf(b0.x, q0, az); aw = fmaf(b0.y, q0, aw);
    }
  }
  float4 bv = *(const float4*)(bias + l * 4);
  ax += bv.x; ay += bv.y; az += bv.z; aw += bv.w;
  if (relu) {
    ax = fmaxf(ax, 0.f); ay = fmaxf(ay, 0.f);
    az = fmaxf(az, 0.f); aw = fmaxf(aw, 0.f);
  }
  if (act) {
    float4 r; r.x = ax; r.y = ay; r.z = az; r.w = aw;
    *(float4*)(H + (size_t)node * 128 + l * 4) = r;
  }
}

// ---------------- Per-pair predictor: z=relu(U[a]+V[b]+bl1); logits=z@Wl2+bl2
// UV fp16 (2 pairs/wave, half-wave = 32 lanes x 4 halves = 256B row).
__global__ __launch_bounds__(256) void k_pair(const __half* __restrict__ UV,
    const int* __restrict__ pt, const int* __restrict__ nt,
    const int* __restrict__ ps, const int* __restrict__ ns,
    const float* __restrict__ bl1, const float* __restrict__ Wl2,
    const float* __restrict__ bl2, float* __restrict__ out,
    int npt, int nnt, int nps, int nns) {
  int gid = blockIdx.x * blockDim.x + threadIdx.x;
  int wave = gid >> 6;
  int lane = threadIdx.x & 63;
  int half = lane >> 5, l = lane & 31;
  int pidx = wave * 2 + half;
  int total = npt + nnt + nps + nns;
  bool act = pidx < total;
  int q = act ? pidx : 0;
  int a, b;
  if (q < npt)               { a = pt[q]; b = pt[npt + q]; }
  else if ((q -= npt) < nnt) { a = nt[q]; b = nt[nnt + q]; }
  else if ((q -= nnt) < nps) { a = ps[q]; b = ps[nps + q]; }
  else { q -= nps;             a = ns[q]; b = ns[nns + q]; }
  uint2 ur = *(const uint2*)(UV + (size_t)a * 256 + l * 4);
  uint2 vr = *(const uint2*)(UV + (size_t)b * 256 + 128 + l * 4);
  float2 u01 = __half22float2(*reinterpret_cast<const __half2*>(&ur.x));
  float2 u23 = __half22float2(*reinterpret_cast<const __half2*>(&ur.y));
  float2 v01 = __half22float2(*reinterpret_cast<const __half2*>(&vr.x));
  float2 v23 = __half22float2(*reinterpret_cast<const __half2*>(&vr.y));
  float4 bb = *(const float4*)(bl1 + l * 4);
  float z0 = fmaxf(u01.x + v01.x + bb.x, 0.f);
  float z1 = fmaxf(u01.y + v01.y + bb.y, 0.f);
  float z2 = fmaxf(u23.x + v23.x + bb.z, 0.f);
  float z3 = fmaxf(u23.y + v23.y + bb.w, 0.f);
  float4 wA = *(const float4*)(Wl2 + l * 8);      // rows 4l,4l+1 x {c0,c1}
  float4 wB = *(const float4*)(Wl2 + l * 8 + 4);  // rows 4l+2,4l+3
  float p0 = fmaf(z0, wA.x, fmaf(z1, wA.z, fmaf(z2, wB.x, z3 * wB.z)));
  float p1 = fmaf(z0, wA.y, fmaf(z1, wA.w, fmaf(z2, wB.y, z3 * wB.w)));
#pragma unroll
  for (int o = 16; o > 0; o >>= 1) {   // reduce within half-wave
    p0 += __shfl_xor(p0, o);
    p1 += __shfl_xor(p1, o);
  }
  if (l == 0 && act) {
    p0 += bl2[0]; p1 += bl2[1];
    float m = fmaxf(p0, p1);
    float lse = m + logf(expf(p0 - m) + expf(p1 - m));
    float2 r; r.x = p0 - lse; r.y = p1 - lse;
    *(float2*)(out + (size_t)pidx * 2) = r;
  }
}

// ============================================================================
extern "C" void kernel_launch(void* const* d_in, const int* in_sizes, int n_in,
                              void* d_out, int out_size, void* d_ws, size_t ws_size,
                              hipStream_t stream) {
  const float* x   = (const float*)d_in[0];
  const float* W0  = (const float*)d_in[1];
  const float* b0  = (const float*)d_in[2];
  const float* W1  = (const float*)d_in[3];
  const float* b1  = (const float*)d_in[4];
  const float* W2  = (const float*)d_in[5];
  const float* b2  = (const float*)d_in[6];
  const float* W3  = (const float*)d_in[7];
  const float* b3  = (const float*)d_in[8];
  const float* Wl1 = (const float*)d_in[9];
  const float* bl1 = (const float*)d_in[10];
  const float* Wl2 = (const float*)d_in[11];
  const float* bl2 = (const float*)d_in[12];
  const int* edge_index = (const int*)d_in[13];
  const int* pt = (const int*)d_in[14];
  const int* nt = (const int*)d_in[15];
  const int* ps = (const int*)d_in[16];
  const int* ns = (const int*)d_in[17];

  const int n   = in_sizes[0] / 128;
  const int E   = in_sizes[13] / 2;
  const int npt = in_sizes[14] / 2;
  const int nnt = in_sizes[15] / 2;
  const int nps = in_sizes[16] / 2;
  const int nns = in_sizes[17] / 2;
  float* out = (float*)d_out;

  // ---- workspace carve (all 256B-aligned regions) ----
  char* ws = (char*)d_ws;
  size_t off = 0;
  auto alloc = [&](size_t bytes) -> void* {
    void* p = ws + off;
    off += (bytes + 255) & ~(size_t)255;
    return p;
  };
  float*  dinv    = (float*)alloc((size_t)n * 4);
  int*    cnt     = (int*)  alloc((size_t)n * 4);
  int*    offs    = (int*)  alloc((size_t)(n + 1) * 4);
  int*    cursor  = (int*)  alloc((size_t)n * 4);
  int*    csum    = (int*)  alloc(256 * 4);
  int*    csr_src = (int*)  alloc((size_t)E * 4);
  float*  csr_w   = (float*)alloc((size_t)E * 4);
  float*  bufA    = (float*)alloc((size_t)n * 128 * 4);   // fp32 H (GEMM input)
  __half* bufT    = (__half*)alloc((size_t)n * 128 * 2);  // fp16 T (GEMM output)
  __half* UV      = (__half*)alloc((size_t)n * 256 * 2);  // fp16 U|V interleaved
  if (off > ws_size) return;  // insufficient scratch -> fail loudly (poisoned out)

  const int* esrc = edge_index;
  const int* edst = edge_index + E;

  // ---- degree + CSR ----
  hipMemsetAsync(cnt, 0, (size_t)n * 4, stream);
  k_count<<<(E + 255) / 256, 256, 0, stream>>>(edst, cnt, E);
  k_dinv<<<(n + 255) / 256, 256, 0, stream>>>(cnt, dinv, n);
  int nc = (n + SCHUNK - 1) / SCHUNK;
  k_chunk_sum<<<nc, 256, 0, stream>>>(cnt, csum, n);
  k_scan_partials<<<1, 64, 0, stream>>>(csum, nc, offs, n);
  k_chunk_scan<<<nc, 256, 0, stream>>>(cnt, csum, offs, n);
  hipMemcpyAsync(cursor, offs, (size_t)n * 4, hipMemcpyDeviceToDevice, stream);
  k_fill<<<(E + 255) / 256, 256, 0, stream>>>(esrc, edst, cursor, csr_src, csr_w, dinv, E);

  const int gblocks = (n + 63) / 64;
  const int awaves  = (n + 1) / 2;           // 2 nodes per wave
  const int ablocks = (awaves + 3) / 4;      // 4 waves/block

  // ---- 4 GCN layers: T(fp16) = A @ W; H(fp32) = Agg(T) ----
  k_gemm<<<gblocks, 256, 0, stream>>>(x, W0, bufT, n, 128);
  k_aggregate<<<ablocks, 256, 0, stream>>>(bufT, bufA, offs, csr_src, csr_w, dinv, b0, n, 1);
  k_gemm<<<gblocks, 256, 0, stream>>>(bufA, W1, bufT, n, 128);
  k_aggregate<<<ablocks, 256, 0, stream>>>(bufT, bufA, offs, csr_src, csr_w, dinv, b1, n, 1);
  k_gemm<<<gblocks, 256, 0, stream>>>(bufA, W2, bufT, n, 128);
  k_aggregate<<<ablocks, 256, 0, stream>>>(bufT, bufA, offs, csr_src, csr_w, dinv, b2, n, 1);
  k_gemm<<<gblocks, 256, 0, stream>>>(bufA, W3, bufT, n, 128);
  k_aggregate<<<ablocks, 256, 0, stream>>>(bufT, bufA, offs, csr_src, csr_w, dinv, b3, n, 0);

  // ---- U = h @ Wl1[:128], V = h @ Wl1[128:], interleaved as UV[n][256] fp16
  k_gemm<<<gblocks, 256, 0, stream>>>(bufA, Wl1, UV, n, 256);
  k_gemm<<<gblocks, 256, 0, stream>>>(bufA, Wl1 + 128 * 128, UV + 128, n, 256);

  // ---- pairs -> log-softmax logits ----
  const int total = npt + nnt + nps + nns;
  const int pwaves = (total + 1) / 2;        // 2 pairs per wave
  k_pair<<<(pwaves + 3) / 4, 256, 0, stream>>>(UV, pt, nt, ps, ns, bl1, Wl2, bl2, out,
                                               npt, nnt, nps, nns);
}

// Round 10
// 797.688 us; speedup vs baseline: 21.7219x; 1.1435x over previous
//
#include <hip/hip_runtime.h>
#include <hip/hip_fp16.h>

// ============================================================================
// GCN link-prediction pipeline.
//   deg/dinv -> CSR(dst, packed uint2) -> 4x (MFMA fp16 GEMM + fp16 aggregate)
//   -> U/V fp16 -> per-pair logits + log_softmax fp32.
// R7 changes vs R6 (912us) [re-submitted R8/R9: acquisition timeouts]:
//  - All 6 GEMMs -> v_mfma_f32_16x16x32_f16 (fp32 accum). Weights converted
//    once/launch to fp16 transposed Wt[n][k] (L2-resident, no LDS).
//    Aggregate writes fp16 H (rounding identical to converting at MFMA input).
//  - k_fill: packed (src,w) uint2 single 8B scattered store (1 line vs 2).
// ============================================================================

typedef _Float16 f16;
using half8 = __attribute__((ext_vector_type(8))) _Float16;
using f32x4 = __attribute__((ext_vector_type(4))) float;

// ---------------- CSR build ----------------
__global__ void k_count(const int* __restrict__ dst, int* __restrict__ cnt, int E) {
  int i = blockIdx.x * blockDim.x + threadIdx.x;
  if (i < E) atomicAdd(&cnt[dst[i]], 1);
}

__global__ void k_dinv(const int* __restrict__ cnt, float* __restrict__ dinv, int n) {
  int i = blockIdx.x * blockDim.x + threadIdx.x;
  if (i < n) dinv[i] = rsqrtf((float)(cnt[i] + 1));  // +1 self-loop; deg>=1 always
}

#define SCHUNK 1024
__global__ void k_chunk_sum(const int* __restrict__ cnt, int* __restrict__ csum, int n) {
  __shared__ int sd[256];
  int c = blockIdx.x, t = threadIdx.x;
  int base = c * SCHUNK;
  int s = 0;
#pragma unroll
  for (int j = 0; j < 4; ++j) {
    int i = base + j * 256 + t;
    if (i < n) s += cnt[i];
  }
  sd[t] = s;
  __syncthreads();
  for (int off = 128; off > 0; off >>= 1) {
    if (t < off) sd[t] += sd[t + off];
    __syncthreads();
  }
  if (t == 0) csum[c] = sd[0];
}

__global__ void k_scan_partials(int* __restrict__ csum, int nc, int* __restrict__ offs, int n) {
  if (threadIdx.x == 0 && blockIdx.x == 0) {
    int run = 0;
    for (int i = 0; i < nc; ++i) { int v = csum[i]; csum[i] = run; run += v; }
    offs[n] = run;  // total = E
  }
}

__global__ void k_chunk_scan(const int* __restrict__ cnt, const int* __restrict__ csum,
                             int* __restrict__ offs, int n) {
  __shared__ int ts[256];
  int c = blockIdx.x, t = threadIdx.x;
  int i0 = c * SCHUNK + t * 4;
  int v0 = 0, v1 = 0, v2 = 0, v3 = 0;
  if (i0 + 0 < n) v0 = cnt[i0 + 0];
  if (i0 + 1 < n) v1 = cnt[i0 + 1];
  if (i0 + 2 < n) v2 = cnt[i0 + 2];
  if (i0 + 3 < n) v3 = cnt[i0 + 3];
  int s = v0 + v1 + v2 + v3;
  ts[t] = s;
  __syncthreads();
  for (int off = 1; off < 256; off <<= 1) {
    int x = (t >= off) ? ts[t - off] : 0;
    __syncthreads();
    ts[t] += x;
    __syncthreads();
  }
  int run = csum[c] + ts[t] - s;  // exclusive prefix for this thread
  if (i0 + 0 < n) { offs[i0 + 0] = run; run += v0; }
  if (i0 + 1 < n) { offs[i0 + 1] = run; run += v1; }
  if (i0 + 2 < n) { offs[i0 + 2] = run; run += v2; }
  if (i0 + 3 < n) { offs[i0 + 3] = run; run += v3; }
}

// Packed edge record: x = src index, y = weight bits. One 8B scattered store.
__global__ void k_fill(const int* __restrict__ src, const int* __restrict__ dst,
                       int* __restrict__ cursor, uint2* __restrict__ csr,
                       const float* __restrict__ dinv, int E) {
  int i = blockIdx.x * blockDim.x + threadIdx.x;
  if (i >= E) return;
  int s = src[i], d = dst[i];
  int pos = atomicAdd(&cursor[d], 1);
  uint2 e;
  e.x = (unsigned)s;
  e.y = __float_as_uint(dinv[s] * dinv[d]);
  csr[pos] = e;
}

// ---------------- Weight prep: Wt[mat][n][k] = (f16) W[mat][k][n] ----------
__global__ void k_wprep(const float* __restrict__ W0, const float* __restrict__ W1,
                        const float* __restrict__ W2, const float* __restrict__ W3,
                        const float* __restrict__ Wl1, f16* __restrict__ Wt) {
  const float* src;
  switch (blockIdx.y) {
    case 0: src = W0; break;
    case 1: src = W1; break;
    case 2: src = W2; break;
    case 3: src = W3; break;
    case 4: src = Wl1; break;
    default: src = Wl1 + 128 * 128; break;
  }
  int t = blockIdx.x * 256 + threadIdx.x;  // 0..16383 (grid.x = 64)
  int nn = t >> 7, k = t & 127;
  Wt[(size_t)blockIdx.y * 16384 + t] = (f16)src[k * 128 + nn];
}

// ---------------- MFMA GEMM: O[M][ldo](fp16) = A[M][128] @ W  --------------
// One wave = 16 output rows x full N=128. A fragment (8 contiguous k/lane)
// loaded once, reused across 8 n-tiles; B from L2-resident Wt[n][k].
// mfma_f32_16x16x32_f16: A lane l: row=l&15, k=8*(l>>4)+i; B lane l: col=l&15,
// k=8*(l>>4)+i; D lane l reg r: row=4*(l>>4)+r, col=l&15.
template <bool AFP32>
__global__ __launch_bounds__(256) void k_gemm_mfma(const void* __restrict__ Av,
    const f16* __restrict__ Wt, __half* __restrict__ O, int M, int ldo) {
  int wid = (int)((blockIdx.x * blockDim.x + threadIdx.x) >> 6);
  int lane = threadIdx.x & 63;
  int m0 = wid << 4;
  if (m0 >= M) return;
  int mr = lane & 15, kg = lane >> 4;
  half8 a[4];
  if (AFP32) {
    const float* A = (const float*)Av;
    const float* p = A + (size_t)(m0 + mr) * 128 + kg * 8;
#pragma unroll
    for (int kk = 0; kk < 4; ++kk) {
      float4 v0 = *(const float4*)(p + kk * 32);
      float4 v1 = *(const float4*)(p + kk * 32 + 4);
      half8 h = {(f16)v0.x, (f16)v0.y, (f16)v0.z, (f16)v0.w,
                 (f16)v1.x, (f16)v1.y, (f16)v1.z, (f16)v1.w};
      a[kk] = h;
    }
  } else {
    const f16* A = (const f16*)Av;
    const f16* p = A + (size_t)(m0 + mr) * 128 + kg * 8;
#pragma unroll
    for (int kk = 0; kk < 4; ++kk) a[kk] = *(const half8*)(p + kk * 32);
  }
  const f16* wp = Wt + (size_t)mr * 128 + kg * 8;  // col n = nt*16 + mr
#pragma unroll 2
  for (int nt = 0; nt < 8; ++nt) {
    const f16* q = wp + (size_t)nt * 16 * 128;
    f32x4 acc = {0.f, 0.f, 0.f, 0.f};
#pragma unroll
    for (int kk = 0; kk < 4; ++kk) {
      half8 b = *(const half8*)(q + kk * 32);
      acc = __builtin_amdgcn_mfma_f32_16x16x32_f16(a[kk], b, acc, 0, 0, 0);
    }
    __half* o = O + (size_t)(m0 + kg * 4) * ldo + nt * 16 + mr;
#pragma unroll
    for (int r = 0; r < 4; ++r) o[(size_t)r * ldo] = (__half)(float)acc[r];
  }
}

// ---------------- Pull aggregation: H(fp16)[i] = sum_e w_e*T[src_e] + di^2*T[i] + b
// T fp16 (256B/row gather), fp32 accumulate, H out fp16 (next GEMM's A).
// 2 nodes per wave: half-wave = 32 lanes x 4 halves. Unroll x4 gathers.
__global__ __launch_bounds__(256) void k_aggregate(const __half* __restrict__ T,
    __half* __restrict__ H, const int* __restrict__ offs,
    const uint2* __restrict__ csr, const float* __restrict__ dinv,
    const float* __restrict__ bias, int n, int relu) {
  int gid = blockIdx.x * blockDim.x + threadIdx.x;
  int wave = gid >> 6;
  int lane = threadIdx.x & 63;
  int half = lane >> 5, l = lane & 31;
  int node = wave * 2 + half;
  bool act = node < n;
  int nd = act ? node : (n - 1);
  float di = dinv[nd];
  float w0 = di * di;
  uint2 tr = *(const uint2*)(T + (size_t)nd * 128 + l * 4);
  float2 t01 = __half22float2(*reinterpret_cast<const __half2*>(&tr.x));
  float2 t23 = __half22float2(*reinterpret_cast<const __half2*>(&tr.y));
  float ax = t01.x * w0, ay = t01.y * w0, az = t23.x * w0, aw = t23.y * w0;
  int e0 = offs[nd], e1 = offs[nd + 1];
  int base = half << 5;
  for (int eb = e0; eb < e1; eb += 32) {
    int m = e1 - eb; if (m > 32) m = 32;
    int s = 0; float wv = 0.f;
    if (l < m) { uint2 e = csr[eb + l]; s = (int)e.x; wv = __uint_as_float(e.y); }
    int j = 0;
    for (; j + 4 <= m; j += 4) {
      int   s0 = __shfl(s,  base + j + 0); float q0 = __shfl(wv, base + j + 0);
      int   s1 = __shfl(s,  base + j + 1); float q1 = __shfl(wv, base + j + 1);
      int   s2 = __shfl(s,  base + j + 2); float q2 = __shfl(wv, base + j + 2);
      int   s3 = __shfl(s,  base + j + 3); float q3 = __shfl(wv, base + j + 3);
      uint2 r0 = *(const uint2*)(T + (size_t)s0 * 128 + l * 4);
      uint2 r1 = *(const uint2*)(T + (size_t)s1 * 128 + l * 4);
      uint2 r2 = *(const uint2*)(T + (size_t)s2 * 128 + l * 4);
      uint2 r3 = *(const uint2*)(T + (size_t)s3 * 128 + l * 4);
      float2 a0 = __half22float2(*reinterpret_cast<const __half2*>(&r0.x));
      float2 b0 = __half22float2(*reinterpret_cast<const __half2*>(&r0.y));
      float2 a1 = __half22float2(*reinterpret_cast<const __half2*>(&r1.x));
      float2 b1 = __half22float2(*reinterpret_cast<const __half2*>(&r1.y));
      float2 a2 = __half22float2(*reinterpret_cast<const __half2*>(&r2.x));
      float2 b2 = __half22float2(*reinterpret_cast<const __half2*>(&r2.y));
      float2 a3 = __half22float2(*reinterpret_cast<const __half2*>(&r3.x));
      float2 b3 = __half22float2(*reinterpret_cast<const __half2*>(&r3.y));
      ax = fmaf(a0.x, q0, fmaf(a1.x, q1, fmaf(a2.x, q2, fmaf(a3.x, q3, ax))));
      ay = fmaf(a0.y, q0, fmaf(a1.y, q1, fmaf(a2.y, q2, fmaf(a3.y, q3, ay))));
      az = fmaf(b0.x, q0, fmaf(b1.x, q1, fmaf(b2.x, q2, fmaf(b3.x, q3, az))));
      aw = fmaf(b0.y, q0, fmaf(b1.y, q1, fmaf(b2.y, q2, fmaf(b3.y, q3, aw))));
    }
    for (; j < m; ++j) {
      int   s0 = __shfl(s,  base + j); float q0 = __shfl(wv, base + j);
      uint2 r0 = *(const uint2*)(T + (size_t)s0 * 128 + l * 4);
      float2 a0 = __half22float2(*reinterpret_cast<const __half2*>(&r0.x));
      float2 b0 = __half22float2(*reinterpret_cast<const __half2*>(&r0.y));
      ax = fmaf(a0.x, q0, ax); ay = fmaf(a0.y, q0, ay);
      az = fmaf(b0.x, q0, az); aw = fmaf(b0.y, q0, aw);
    }
  }
  float4 bv = *(const float4*)(bias + l * 4);
  ax += bv.x; ay += bv.y; az += bv.z; aw += bv.w;
  if (relu) {
    ax = fmaxf(ax, 0.f); ay = fmaxf(ay, 0.f);
    az = fmaxf(az, 0.f); aw = fmaxf(aw, 0.f);
  }
  if (act) {
    __half2 h01 = __floats2half2_rn(ax, ay);
    __half2 h23 = __floats2half2_rn(az, aw);
    uint2 pk;
    pk.x = *reinterpret_cast<unsigned int*>(&h01);
    pk.y = *reinterpret_cast<unsigned int*>(&h23);
    *reinterpret_cast<uint2*>(H + (size_t)node * 128 + l * 4) = pk;
  }
}

// ---------------- Per-pair predictor: z=relu(U[a]+V[b]+bl1); logits=z@Wl2+bl2
// UV fp16 (2 pairs/wave, half-wave = 32 lanes x 4 halves = 256B row).
__global__ __launch_bounds__(256) void k_pair(const __half* __restrict__ UV,
    const int* __restrict__ pt, const int* __restrict__ nt,
    const int* __restrict__ ps, const int* __restrict__ ns,
    const float* __restrict__ bl1, const float* __restrict__ Wl2,
    const float* __restrict__ bl2, float* __restrict__ out,
    int npt, int nnt, int nps, int nns) {
  int gid = blockIdx.x * blockDim.x + threadIdx.x;
  int wave = gid >> 6;
  int lane = threadIdx.x & 63;
  int half = lane >> 5, l = lane & 31;
  int pidx = wave * 2 + half;
  int total = npt + nnt + nps + nns;
  bool act = pidx < total;
  int q = act ? pidx : 0;
  int a, b;
  if (q < npt)               { a = pt[q]; b = pt[npt + q]; }
  else if ((q -= npt) < nnt) { a = nt[q]; b = nt[nnt + q]; }
  else if ((q -= nnt) < nps) { a = ps[q]; b = ps[nps + q]; }
  else { q -= nps;             a = ns[q]; b = ns[nns + q]; }
  uint2 ur = *(const uint2*)(UV + (size_t)a * 256 + l * 4);
  uint2 vr = *(const uint2*)(UV + (size_t)b * 256 + 128 + l * 4);
  float2 u01 = __half22float2(*reinterpret_cast<const __half2*>(&ur.x));
  float2 u23 = __half22float2(*reinterpret_cast<const __half2*>(&ur.y));
  float2 v01 = __half22float2(*reinterpret_cast<const __half2*>(&vr.x));
  float2 v23 = __half22float2(*reinterpret_cast<const __half2*>(&vr.y));
  float4 bb = *(const float4*)(bl1 + l * 4);
  float z0 = fmaxf(u01.x + v01.x + bb.x, 0.f);
  float z1 = fmaxf(u01.y + v01.y + bb.y, 0.f);
  float z2 = fmaxf(u23.x + v23.x + bb.z, 0.f);
  float z3 = fmaxf(u23.y + v23.y + bb.w, 0.f);
  float4 wA = *(const float4*)(Wl2 + l * 8);      // rows 4l,4l+1 x {c0,c1}
  float4 wB = *(const float4*)(Wl2 + l * 8 + 4);  // rows 4l+2,4l+3
  float p0 = fmaf(z0, wA.x, fmaf(z1, wA.z, fmaf(z2, wB.x, z3 * wB.z)));
  float p1 = fmaf(z0, wA.y, fmaf(z1, wA.w, fmaf(z2, wB.y, z3 * wB.w)));
#pragma unroll
  for (int o = 16; o > 0; o >>= 1) {   // reduce within half-wave
    p0 += __shfl_xor(p0, o);
    p1 += __shfl_xor(p1, o);
  }
  if (l == 0 && act) {
    p0 += bl2[0]; p1 += bl2[1];
    float m = fmaxf(p0, p1);
    float lse = m + logf(expf(p0 - m) + expf(p1 - m));
    float2 r; r.x = p0 - lse; r.y = p1 - lse;
    *(float2*)(out + (size_t)pidx * 2) = r;
  }
}

// ============================================================================
extern "C" void kernel_launch(void* const* d_in, const int* in_sizes, int n_in,
                              void* d_out, int out_size, void* d_ws, size_t ws_size,
                              hipStream_t stream) {
  const float* x   = (const float*)d_in[0];
  const float* W0  = (const float*)d_in[1];
  const float* b0  = (const float*)d_in[2];
  const float* W1  = (const float*)d_in[3];
  const float* b1  = (const float*)d_in[4];
  const float* W2  = (const float*)d_in[5];
  const float* b2  = (const float*)d_in[6];
  const float* W3  = (const float*)d_in[7];
  const float* b3  = (const float*)d_in[8];
  const float* Wl1 = (const float*)d_in[9];
  const float* bl1 = (const float*)d_in[10];
  const float* Wl2 = (const float*)d_in[11];
  const float* bl2 = (const float*)d_in[12];
  const int* edge_index = (const int*)d_in[13];
  const int* pt = (const int*)d_in[14];
  const int* nt = (const int*)d_in[15];
  const int* ps = (const int*)d_in[16];
  const int* ns = (const int*)d_in[17];

  const int n   = in_sizes[0] / 128;
  const int E   = in_sizes[13] / 2;
  const int npt = in_sizes[14] / 2;
  const int nnt = in_sizes[15] / 2;
  const int nps = in_sizes[16] / 2;
  const int nns = in_sizes[17] / 2;
  float* out = (float*)d_out;

  // ---- workspace carve (all 256B-aligned regions) ----
  char* ws = (char*)d_ws;
  size_t off = 0;
  auto alloc = [&](size_t bytes) -> void* {
    void* p = ws + off;
    off += (bytes + 255) & ~(size_t)255;
    return p;
  };
  float*  dinv    = (float*)alloc((size_t)n * 4);
  int*    cnt     = (int*)  alloc((size_t)n * 4);
  int*    offs    = (int*)  alloc((size_t)(n + 1) * 4);
  int*    cursor  = (int*)  alloc((size_t)n * 4);
  int*    csum    = (int*)  alloc(256 * 4);
  uint2*  csr     = (uint2*)alloc((size_t)E * 8);          // packed (src, w)
  f16*    Wt      = (f16*)  alloc((size_t)6 * 16384 * 2);  // fp16 W^T x6
  __half* bufH    = (__half*)alloc((size_t)n * 128 * 2);   // fp16 H (GEMM in)
  __half* bufT    = (__half*)alloc((size_t)n * 128 * 2);   // fp16 T (GEMM out)
  __half* UV      = (__half*)alloc((size_t)n * 256 * 2);   // fp16 U|V interleaved
  if (off > ws_size) return;  // insufficient scratch -> fail loudly (poisoned out)

  const int* esrc = edge_index;
  const int* edst = edge_index + E;

  // ---- degree + CSR + weight prep ----
  hipMemsetAsync(cnt, 0, (size_t)n * 4, stream);
  k_count<<<(E + 255) / 256, 256, 0, stream>>>(edst, cnt, E);
  k_dinv<<<(n + 255) / 256, 256, 0, stream>>>(cnt, dinv, n);
  int nc = (n + SCHUNK - 1) / SCHUNK;
  k_chunk_sum<<<nc, 256, 0, stream>>>(cnt, csum, n);
  k_scan_partials<<<1, 64, 0, stream>>>(csum, nc, offs, n);
  k_chunk_scan<<<nc, 256, 0, stream>>>(cnt, csum, offs, n);
  hipMemcpyAsync(cursor, offs, (size_t)n * 4, hipMemcpyDeviceToDevice, stream);
  k_fill<<<(E + 255) / 256, 256, 0, stream>>>(esrc, edst, cursor, csr, dinv, E);
  dim3 wpgrid(64, 6);
  k_wprep<<<wpgrid, 256, 0, stream>>>(W0, W1, W2, W3, Wl1, Wt);

  const int gwaves  = (n + 15) / 16;
  const int gblocks = (gwaves * 64 + 255) / 256;
  const int awaves  = (n + 1) / 2;           // 2 nodes per wave
  const int ablocks = (awaves + 3) / 4;      // 4 waves/block

  // ---- 4 GCN layers: T(fp16) = A @ W (MFMA); H(fp16) = Agg(T) ----
  k_gemm_mfma<true ><<<gblocks, 256, 0, stream>>>(x,    Wt,               bufT, n, 128);
  k_aggregate<<<ablocks, 256, 0, stream>>>(bufT, bufH, offs, csr, dinv, b0, n, 1);
  k_gemm_mfma<false><<<gblocks, 256, 0, stream>>>(bufH, Wt + 1 * 16384, bufT, n, 128);
  k_aggregate<<<ablocks, 256, 0, stream>>>(bufT, bufH, offs, csr, dinv, b1, n, 1);
  k_gemm_mfma<false><<<gblocks, 256, 0, stream>>>(bufH, Wt + 2 * 16384, bufT, n, 128);
  k_aggregate<<<ablocks, 256, 0, stream>>>(bufT, bufH, offs, csr, dinv, b2, n, 1);
  k_gemm_mfma<false><<<gblocks, 256, 0, stream>>>(bufH, Wt + 3 * 16384, bufT, n, 128);
  k_aggregate<<<ablocks, 256, 0, stream>>>(bufT, bufH, offs, csr, dinv, b3, n, 0);

  // ---- U = h @ Wl1[:128], V = h @ Wl1[128:], interleaved as UV[n][256] fp16
  k_gemm_mfma<false><<<gblocks, 256, 0, stream>>>(bufH, Wt + 4 * 16384, UV,       n, 256);
  k_gemm_mfma<false><<<gblocks, 256, 0, stream>>>(bufH, Wt + 5 * 16384, UV + 128, n, 256);

  // ---- pairs -> log-softmax logits ----
  const int total = npt + nnt + nps + nns;
  const int pwaves = (total + 1) / 2;        // 2 pairs per wave
  k_pair<<<(pwaves + 3) / 4, 256, 0, stream>>>(UV, pt, nt, ps, ns, bl1, Wl2, bl2, out,
                                               npt, nnt, nps, nns);
}